// Round 13
// baseline (242.596 us; speedup 1.0000x reference)
//
#include <hip/hip_runtime.h>

// Problem constants: B=2, N=1024, U=V=512, F_IN=1, F=64, L=4
#define NTOT 1024
#define HALF 512
#define NBLK 256
#define NTHR 512

struct EdgeS  { float adjr[8][1024]; float nfv[1024]; float ein[8][64]; };
struct LayerS { float part[8][8][64]; float e[8][64]; float x[8][64];
                float agg[8][64]; float msg[8][64]; };
union SMem { EdgeS e; LayerS l; };

static __device__ __forceinline__ void st_coh(float* p, float v) {
    __hip_atomic_store(p, v, __ATOMIC_RELAXED, __HIP_MEMORY_SCOPE_AGENT);
}
static __device__ __forceinline__ float ld_coh(const float* p) {
    return __hip_atomic_load((float*)p, __ATOMIC_RELAXED, __HIP_MEMORY_SCOPE_AGENT);
}
// Poll until an encoded value is present (enc >= 1.0; poison 0xAA.. = -1.2e-13
// and zero-init both rejected). Bounded: degrades to wrong result, not a hang.
static __device__ __forceinline__ float poll1(const float* p) {
    float v = ld_coh(p);
    int spins = 0;
    while (!(v >= 1.0f)) {
        if (++spins > (1 << 20)) break;
        __builtin_amdgcn_s_sleep(1);
        v = ld_coh(p);
    }
    return v;
}

__global__ void __launch_bounds__(NTHR, 2) k_all(
    const float* __restrict__ nf, const float* __restrict__ adj,
    const float* __restrict__ wvu, const float* __restrict__ Wi,
    const float* __restrict__ bi, const float* __restrict__ Wee,
    const float* __restrict__ Wef, const float* __restrict__ Wm,
    const float* __restrict__ Wu, float* __restrict__ out,
    float* __restrict__ xe0, float* __restrict__ xe1,
    float* __restrict__ xe2, float* __restrict__ xe3,
    float* __restrict__ partials, float* __restrict__ maxenc)
{
    __shared__ SMem sm;
    __shared__ float pred[64][8];
    __shared__ float snorm[8];
    __shared__ float swred[8];
    const int bid = blockIdx.x, tid = threadIdx.x;
    const int g0 = bid * 8;
    const int b = g0 >> 10, i0 = g0 & 1023;
    const bool top = (i0 < 512);
    const int lane = tid & 63, wave = tid >> 6;

    // ---------- Phase A: norm colsum partial (pure encoded store) + x0 ------
    {
        int cb = bid >> 7, sub = bid & 127;
        int cc = sub & 1, rc = sub >> 1;
        int col = cc * 512 + tid;
        const float* p = adj + (size_t)cb * NTOT * NTOT + (size_t)rc * 16 * NTOT + col;
        float s = 0.f;
#pragma unroll
        for (int r = 0; r < 16; ++r) s += 1.0f - p[(size_t)r * NTOT];
        st_coh(&partials[(size_t)(cb * 64 + rc) * 1024 + col], s + 1.0f); // exact ints
    }
    float xreg;   // own x[g0+q][f] (decoded), lives in a register across layers
    {
        int e = bid * NTHR + tid;       // == (g0+q)*64 + f
        int f0 = e & 63, bn = e >> 6;
        xreg = fmaxf(fmaf(nf[bn], Wi[f0], bi[f0]), 0.f);
        st_coh(&xe0[e], xreg + 1.0f);
    }

    // ---------- stage wqv + adjr + nfv (no cross-block deps) ----------------
    __shared__ float wqv[512][8];   // persistent: W for this block's 8 rows
    if (top) {
        const float* src = wvu + (size_t)b * 262144 + (size_t)tid * 512 + i0;
        float4 v0 = *(const float4*)(src);
        float4 v1 = *(const float4*)(src + 4);
        *(float4*)&wqv[tid][0] = v0;
        *(float4*)&wqv[tid][4] = v1;
    } else {
        const float* wsrc = wvu + (size_t)b * 262144 + (size_t)(i0 - 512) * 512;
        for (int t = tid; t < 4096; t += NTHR) {
            int r = t >> 9, j = t & 511;
            wqv[j][r] = wsrc[r * 512 + j];
        }
    }
    {
        const float4* asrc = (const float4*)(adj + (size_t)b * 1048576 + (size_t)i0 * 1024);
        float4* adst = (float4*)sm.e.adjr;
        for (int t = tid; t < 2048; t += NTHR) adst[t] = asrc[t];
        if (tid < 256) ((float4*)sm.e.nfv)[tid] = ((const float4*)(nf + b * 1024))[tid];
    }
    __syncthreads();

    // ---------- edge compute needing no cross-block data --------------------
    const int row = wave;
    float acc;
    {
        int sameoff = top ? 0 : 512;
        int crossoff = top ? 512 : 0;
        float sp = 0.f, smv = 0.f;
#pragma unroll
        for (int it = 0; it < 8; ++it) {
            int j = sameoff + it * 64 + lane;
            float m = 1.0f - sm.e.adjr[row][j];
            float x = sm.e.nfv[j];
            sp = fmaf(m, fmaxf(x, 0.f), sp);
            smv = fmaf(m, fmaxf(-x, 0.f), smv);
        }
#pragma unroll
        for (int o = 32; o > 0; o >>= 1) {
            sp += __shfl_xor(sp, o, 64);
            smv += __shfl_xor(smv, o, 64);
        }
        float W0 = 0.f, W1 = 0.f;
        if (lane < 63) { W0 = Wee[lane]; W1 = Wee[63 + lane]; }
        acc = fabsf(W1) * (W1 > 0.f ? sp : smv);
        const float* arow = &sm.e.adjr[row][crossoff];
        const float* nrow = &sm.e.nfv[crossoff];
#pragma unroll 4
        for (int qq = 0; qq < 128; ++qq) {
            float4 a4 = *(const float4*)(arow + qq * 4);
            float4 n4 = *(const float4*)(nrow + qq * 4);
            float w0 = wqv[qq * 4 + 0][row];
            float w1 = wqv[qq * 4 + 1][row];
            float w2 = wqv[qq * 4 + 2][row];
            float w3 = wqv[qq * 4 + 3][row];
            float c;
            c = fmaxf(fmaf(w0, W0, n4.x * W1), 0.f); acc = fmaf(1.0f - a4.x, c, acc);
            c = fmaxf(fmaf(w1, W0, n4.y * W1), 0.f); acc = fmaf(1.0f - a4.y, c, acc);
            c = fmaxf(fmaf(w2, W0, n4.z * W1), 0.f); acc = fmaf(1.0f - a4.z, c, acc);
            c = fmaxf(fmaf(w3, W0, n4.w * W1), 0.f); acc = fmaf(1.0f - a4.w, c, acc);
        }
    }

    // ---------- norms via dataflow: poll partials, then block-max exchange --
    {
        int rc = tid >> 3, c = tid & 7;
        float pv = poll1(&partials[(size_t)(b * 64 + rc) * 1024 + i0 + c]);
        pred[rc][c] = pv - 1.0f;
    }
    __syncthreads();
    if (tid < 8) {
        float s = 0.f;
#pragma unroll 16
        for (int r = 0; r < 64; ++r) s += pred[r][tid];
        snorm[tid] = fmaxf(s, 1.0f);
    }
    __syncthreads();
    if (tid == 0) {
        float m = snorm[0];
#pragma unroll
        for (int u = 1; u < 8; ++u) m = fmaxf(m, snorm[u]);
        st_coh(&maxenc[bid * 16], m);     // norms >= 1: self-sentinel
    }
    {
        float m = 1.0f;
        if (tid < NBLK) m = poll1(&maxenc[tid * 16]);
#pragma unroll
        for (int o = 32; o > 0; o >>= 1) m = fmaxf(m, __shfl_xor(m, o, 64));
        if (lane == 0) swred[wave] = m;
    }
    __syncthreads();

    // ---------- finish edge: divide, 64x64 matmul (Wef from global/L1) ------
    float eval;
    {
        float nv = snorm[row];
        float nmaxv = fmaxf(fmaxf(fmaxf(swred[0], swred[1]), fmaxf(swred[2], swred[3])),
                            fmaxf(fmaxf(swred[4], swred[5]), fmaxf(swred[6], swred[7])));
        float ein = (lane < 63) ? (acc * (1.0f / nv)) : (nv / nmaxv);
        sm.e.ein[row][lane] = ein;
        __syncthreads();
        float acc2 = 0.f;
#pragma unroll 8
        for (int c = 0; c < 64; ++c)
            acc2 = fmaf(sm.e.ein[row][c], Wef[c * 64 + lane], acc2);
        eval = fmaxf(acc2, 0.f);
    }
    __syncthreads();   // EdgeS dead; union switches to LayerS

    // ---------- layers: pure dataflow, per-element encoded polls ------------
    const int f = lane, q = wave;
    sm.l.e[q][f] = eval;
    sm.l.x[q][f] = xreg;
    __syncthreads();
    const float rnorm = 1.0f / snorm[q];

    for (int l = 0; l < 4; ++l) {
        const float* WmL = Wm + l * 8192;
        const float* WuL = Wu + l * 8192;
        // cross-block-independent work first (e@Wm2, own-x@Wu1)
        float emsg = 0.f, hx = 0.f;
#pragma unroll 8
        for (int c = 0; c < 64; ++c) {
            emsg = fmaf(sm.l.e[q][c], WmL[(64 + c) * 64 + f], emsg);
            hx   = fmaf(sm.l.x[q][c], WuL[c * 64 + f], hx);
        }
        const float* xin = (l == 0) ? xe0 : (l == 1) ? xe1 : (l == 2) ? xe2 : xe3;
        const float* xb = xin + ((size_t)b * 1024 + (top ? 512 : 0)) * 64 + f;
        float a0 = 0, a1 = 0, a2 = 0, a3 = 0, a4 = 0, a5 = 0, a6 = 0, a7 = 0;
        const int jbase = q * 64;
#pragma unroll
        for (int hh = 0; hh < 2; ++hh) {
            float xv[32];
#pragma unroll
            for (int u = 0; u < 32; ++u)
                xv[u] = ld_coh(xb + (size_t)(jbase + hh * 32 + u) * 64);
#pragma unroll
            for (int u = 0; u < 32; ++u) {
                int spins = 0;
                while (!(xv[u] >= 1.0f)) {
                    if (++spins > (1 << 20)) break;
                    __builtin_amdgcn_s_sleep(1);
                    xv[u] = ld_coh(xb + (size_t)(jbase + hh * 32 + u) * 64);
                }
                xv[u] -= 1.0f;   // decode
            }
#pragma unroll
            for (int u = 0; u < 32; ++u) {
                int j = jbase + hh * 32 + u;
                float4 w0 = *(const float4*)&wqv[j][0];
                float4 w1 = *(const float4*)&wqv[j][4];
                a0 = fmaf(w0.x, xv[u], a0); a1 = fmaf(w0.y, xv[u], a1);
                a2 = fmaf(w0.z, xv[u], a2); a3 = fmaf(w0.w, xv[u], a3);
                a4 = fmaf(w1.x, xv[u], a4); a5 = fmaf(w1.y, xv[u], a5);
                a6 = fmaf(w1.z, xv[u], a6); a7 = fmaf(w1.w, xv[u], a7);
            }
        }
        sm.l.part[q][0][f] = a0; sm.l.part[q][1][f] = a1;
        sm.l.part[q][2][f] = a2; sm.l.part[q][3][f] = a3;
        sm.l.part[q][4][f] = a4; sm.l.part[q][5][f] = a5;
        sm.l.part[q][6][f] = a6; sm.l.part[q][7][f] = a7;
        __syncthreads();
        float aggv = 0.f;
#pragma unroll
        for (int w = 0; w < 8; ++w) aggv += sm.l.part[w][q][f];
        aggv *= rnorm;
        sm.l.agg[q][f] = aggv;
        __syncthreads();
        float mv = emsg;
#pragma unroll 8
        for (int c = 0; c < 64; ++c) mv = fmaf(sm.l.agg[q][c], WmL[c * 64 + f], mv);
        mv = fmaxf(mv, 0.f);
        sm.l.msg[q][f] = mv;
        __syncthreads();
        float h = hx;
#pragma unroll 8
        for (int c = 0; c < 64; ++c) h = fmaf(sm.l.msg[q][c], WuL[(64 + c) * 64 + f], h);
        if (l != 3) {
            h = fmaxf(h, 0.f);
            float* xout = (l == 0) ? xe1 : (l == 1) ? xe2 : xe3;
            st_coh(&xout[(size_t)(g0 + q) * 64 + f], h + 1.0f);   // encoded publish
            xreg = h;
            sm.l.x[q][f] = h;     // own-wave write, own-wave read next iter
        } else {
            out[(size_t)(g0 + q) * 64 + f] = h;
        }
    }
}

extern "C" void kernel_launch(void* const* d_in, const int* in_sizes, int n_in,
                              void* d_out, int out_size, void* d_ws, size_t ws_size,
                              hipStream_t stream) {
    const float* nf  = (const float*)d_in[0];
    const float* adj = (const float*)d_in[1];
    const float* wvu = (const float*)d_in[2];
    const float* Wi  = (const float*)d_in[3];
    const float* bi  = (const float*)d_in[4];
    const float* Wee = (const float*)d_in[5];
    const float* Wef = (const float*)d_in[6];
    const float* Wm  = (const float*)d_in[7];
    const float* Wu  = (const float*)d_in[8];
    float* out = (float*)d_out;
    float* ws = (float*)d_ws;

    float* xe0      = ws;                // 131072 floats each, write-once
    float* xe1      = ws + 131072;
    float* xe2      = ws + 262144;
    float* xe3      = ws + 393216;
    float* partials = ws + 524288;       // [2][64][1024] encoded colsum chunks
    float* maxenc   = ws + 655360;       // 256 line-padded block maxima

    // No memset: nothing needs zero-init. Poison (0xAA) / zeros both read as
    // "absent" (< 1.0f) by the dataflow polls.
    k_all<<<NBLK, NTHR, 0, stream>>>(nf, adj, wvu, Wi, bi, Wee, Wef, Wm, Wu,
                                     out, xe0, xe1, xe2, xe3, partials, maxenc);
}

// Round 14
// 213.014 us; speedup vs baseline: 1.1389x; 1.1389x over previous
//
#include <hip/hip_runtime.h>

// Problem constants: B=2, N=1024, U=V=512, F_IN=1, F=64, L=4
#define NTOT 1024
#define HALF 512
#define NBLK 256
#define NTHR 512

// LayerS (24 KB) is smaller than offsetof(EdgeS, nfv) (32 KB), so nfv
// survives the union switch into the layer phase (needed for local x0 gen).
struct EdgeS  { float adjr[8][1024]; float nfv[1024]; float ein[8][64]; };
struct LayerS { float part[8][8][64]; float e[8][64]; float x[8][64];
                float agg[8][64]; float msg[8][64]; };
union SMem { EdgeS e; LayerS l; };

static __device__ __forceinline__ void st_coh(float* p, float v) {
    __hip_atomic_store(p, v, __ATOMIC_RELAXED, __HIP_MEMORY_SCOPE_AGENT);
}
static __device__ __forceinline__ float ld_coh(const float* p) {
    return __hip_atomic_load((float*)p, __ATOMIC_RELAXED, __HIP_MEMORY_SCOPE_AGENT);
}
// Poll an encoded float (present iff >= 1.0; 0xAA poison and zeros both read
// as absent). Bounded: degrades to wrong results, never hangs.
static __device__ __forceinline__ float poll1(const float* p) {
    float v = ld_coh(p);
    int spins = 0;
    while (!(v >= 1.0f)) {
        if (++spins > (1 << 22)) break;
        __builtin_amdgcn_s_sleep(2);
        v = ld_coh(p);
    }
    return v;
}

// Flag relay. Arrive: drain own coherent stores, block barrier (also makes
// this iteration's LDS x visible), one flag store. Wait: wave 0's lanes spin
// independently on one producer flag each (no block-wide sweep), then one
// __syncthreads. Flags use poison-as-unset (poll ==1), so no zero-init.
static __device__ __forceinline__ void arrive(int* flags, int idx) {
    asm volatile("s_waitcnt vmcnt(0) lgkmcnt(0)" ::: "memory");
    __syncthreads();
    if (threadIdx.x == 0)
        __hip_atomic_store(&flags[(idx * NBLK + blockIdx.x) * 16], 1,
                           __ATOMIC_RELAXED, __HIP_MEMORY_SCOPE_AGENT);
}
static __device__ __forceinline__ void wait64(const int* flags, int idx, int pbase) {
    if (threadIdx.x < 64) {
        const int* fp = &flags[(idx * NBLK + pbase + threadIdx.x) * 16];
        int spins = 0;
        while (__hip_atomic_load((int*)fp, __ATOMIC_RELAXED,
                                 __HIP_MEMORY_SCOPE_AGENT) != 1) {
            if (++spins > (1 << 22)) break;
            __builtin_amdgcn_s_sleep(1);
        }
    }
    __syncthreads();
}

__global__ void __launch_bounds__(NTHR, 2) k_all(
    const float* __restrict__ nf, const float* __restrict__ adj,
    const float* __restrict__ wvu, const float* __restrict__ Wi,
    const float* __restrict__ bi, const float* __restrict__ Wee,
    const float* __restrict__ Wef, const float* __restrict__ Wm,
    const float* __restrict__ Wu, float* __restrict__ out,
    float* __restrict__ xA, float* __restrict__ xB,
    float* __restrict__ maxenc, int* __restrict__ flags)
{
    __shared__ SMem sm;
    __shared__ float wqv[512][8];   // persistent: W for this block's 8 rows
    __shared__ float npart[64][8];
    __shared__ float snorm[8];
    __shared__ float smax[256];
    __shared__ float snmax;
    const int bid = blockIdx.x, tid = threadIdx.x;
    const int g0 = bid * 8;
    const int b = g0 >> 10, i0 = g0 & 1023;
    const bool top = (i0 < 512);
    const int lane = tid & 63, wave = tid >> 6;
    const int pbase = b * 128 + (top ? 64 : 0);   // producers of cross-half x

    // ---------- own 8 norm columns, locally (no cross-block dependency) -----
    {
        int c = tid & 7, g = tid >> 3;   // g in 0..63, 16 rows each
        const float* colp = adj + (size_t)b * 1048576 + (size_t)g * 16384 + i0 + c;
        float s = 0.f;
#pragma unroll
        for (int r = 0; r < 16; ++r) s += 1.0f - colp[(size_t)r * 1024];
        npart[g][c] = s;                 // exact small integers
    }
    // ---------- stage wqv + adjr + nfv --------------------------------------
    if (top) {
        const float* src = wvu + (size_t)b * 262144 + (size_t)tid * 512 + i0;
        float4 v0 = *(const float4*)(src);
        float4 v1 = *(const float4*)(src + 4);
        *(float4*)&wqv[tid][0] = v0;
        *(float4*)&wqv[tid][4] = v1;
    } else {
        const float* wsrc = wvu + (size_t)b * 262144 + (size_t)(i0 - 512) * 512;
        for (int t = tid; t < 4096; t += NTHR) {
            int r = t >> 9, j = t & 511;
            wqv[j][r] = wsrc[r * 512 + j];
        }
    }
    {
        const float4* asrc = (const float4*)(adj + (size_t)b * 1048576 + (size_t)i0 * 1024);
        float4* adst = (float4*)sm.e.adjr;
        for (int t = tid; t < 2048; t += NTHR) adst[t] = asrc[t];
        if (tid < 256) ((float4*)sm.e.nfv)[tid] = ((const float4*)(nf + b * 1024))[tid];
    }
    __syncthreads();
    if (tid < 8) {
        float s = 0.f;
#pragma unroll 16
        for (int g = 0; g < 64; ++g) s += npart[g][tid];
        snorm[tid] = fmaxf(s, 1.0f);
    }
    __syncthreads();
    if (tid == 0) {   // publish block max ASAP (self-sentinel: value >= 1)
        float m = snorm[0];
#pragma unroll
        for (int u = 1; u < 8; ++u) m = fmaxf(m, snorm[u]);
        st_coh(&maxenc[bid * 16], m);
    }
    const float Wif = Wi[lane];
    const float bif = bi[lane];
    float xreg = fmaxf(fmaf(nf[b * 1024 + i0 + wave], Wif, bif), 0.f);

    // ---------- edge compute (no cross-block data) --------------------------
    const int row = wave;
    float acc;
    {
        int sameoff = top ? 0 : 512;
        int crossoff = top ? 512 : 0;
        float sp = 0.f, smv = 0.f;
#pragma unroll
        for (int it = 0; it < 8; ++it) {
            int j = sameoff + it * 64 + lane;
            float m = 1.0f - sm.e.adjr[row][j];
            float x = sm.e.nfv[j];
            sp = fmaf(m, fmaxf(x, 0.f), sp);
            smv = fmaf(m, fmaxf(-x, 0.f), smv);
        }
#pragma unroll
        for (int o = 32; o > 0; o >>= 1) {
            sp += __shfl_xor(sp, o, 64);
            smv += __shfl_xor(smv, o, 64);
        }
        float W0 = 0.f, W1 = 0.f;
        if (lane < 63) { W0 = Wee[lane]; W1 = Wee[63 + lane]; }
        acc = fabsf(W1) * (W1 > 0.f ? sp : smv);
        const float* arow = &sm.e.adjr[row][crossoff];
        const float* nrow = &sm.e.nfv[crossoff];
#pragma unroll 4
        for (int qq = 0; qq < 128; ++qq) {
            float4 a4 = *(const float4*)(arow + qq * 4);
            float4 n4 = *(const float4*)(nrow + qq * 4);
            float w0 = wqv[qq * 4 + 0][row];
            float w1 = wqv[qq * 4 + 1][row];
            float w2 = wqv[qq * 4 + 2][row];
            float w3 = wqv[qq * 4 + 3][row];
            float c;
            c = fmaxf(fmaf(w0, W0, n4.x * W1), 0.f); acc = fmaf(1.0f - a4.x, c, acc);
            c = fmaxf(fmaf(w1, W0, n4.y * W1), 0.f); acc = fmaf(1.0f - a4.y, c, acc);
            c = fmaxf(fmaf(w2, W0, n4.z * W1), 0.f); acc = fmaf(1.0f - a4.z, c, acc);
            c = fmaxf(fmaf(w3, W0, n4.w * W1), 0.f); acc = fmaf(1.0f - a4.w, c, acc);
        }
    }
    // ---------- global max: poll the 256 block maxima (hidden by edge work) -
    if (tid < 256) smax[tid] = poll1(&maxenc[tid * 16]);
    __syncthreads();
    if (tid < 64) {
        float m = fmaxf(fmaxf(smax[tid], smax[tid + 64]),
                        fmaxf(smax[tid + 128], smax[tid + 192]));
#pragma unroll
        for (int o = 32; o > 0; o >>= 1) m = fmaxf(m, __shfl_xor(m, o, 64));
        if (tid == 0) snmax = m;
    }
    __syncthreads();

    // ---------- finish edge: divide, 64x64 matmul (Wef via L1) --------------
    float eval;
    {
        float nv = snorm[row];
        float nmaxv = snmax;
        float ein = (lane < 63) ? (acc * (1.0f / nv)) : (nv / nmaxv);
        sm.e.ein[row][lane] = ein;
        __syncthreads();
        float acc2 = 0.f;
#pragma unroll 8
        for (int c = 0; c < 64; ++c)
            acc2 = fmaf(sm.e.ein[row][c], Wef[c * 64 + lane], acc2);
        eval = fmaxf(acc2, 0.f);
    }
    __syncthreads();   // EdgeS adjr/ein dead; LayerS (24 KB) leaves nfv intact

    // ---------- layers ------------------------------------------------------
    const int f = lane, q = wave;
    sm.l.e[q][f] = eval;
    sm.l.x[q][f] = xreg;
    __syncthreads();
    const float rnorm = 1.0f / snorm[q];
    const int crossoff = top ? 512 : 0;

    for (int l = 0; l < 4; ++l) {
        const float* WmL = Wm + l * 8192;
        const float* WuL = Wu + l * 8192;
        // cross-block-independent work first (e@Wm2, own-x@Wu1)
        float emsg = 0.f, hx = 0.f;
#pragma unroll 8
        for (int c = 0; c < 64; ++c) {
            emsg = fmaf(sm.l.e[q][c], WmL[(64 + c) * 64 + f], emsg);
            hx   = fmaf(sm.l.x[q][c], WuL[c * 64 + f], hx);
        }
        if (l > 0) wait64(flags, l - 1, pbase);   // cross-half x^l visible

        const float* xin = (l == 1) ? xA : (l == 2) ? xB : xA;  // l==0 unused
        const float* xb = xin + ((size_t)b * 1024 + (top ? 512 : 0)) * 64 + f;
        float a0 = 0, a1 = 0, a2 = 0, a3 = 0, a4 = 0, a5 = 0, a6 = 0, a7 = 0;
        const int jbase = q * 64;
#pragma unroll
        for (int hh = 0; hh < 2; ++hh) {
            float xv[32];
            if (l == 0) {
                // regenerate cross-half x0 locally: relu(nf*Wi + bi)
#pragma unroll
                for (int u = 0; u < 32; ++u)
                    xv[u] = fmaxf(fmaf(sm.e.nfv[crossoff + jbase + hh * 32 + u],
                                       Wif, bif), 0.f);
            } else {
#pragma unroll
                for (int u = 0; u < 32; ++u)
                    xv[u] = ld_coh(xb + (size_t)(jbase + hh * 32 + u) * 64);
            }
#pragma unroll
            for (int u = 0; u < 32; ++u) {
                int j = jbase + hh * 32 + u;
                float4 w0 = *(const float4*)&wqv[j][0];
                float4 w1 = *(const float4*)&wqv[j][4];
                a0 = fmaf(w0.x, xv[u], a0); a1 = fmaf(w0.y, xv[u], a1);
                a2 = fmaf(w0.z, xv[u], a2); a3 = fmaf(w0.w, xv[u], a3);
                a4 = fmaf(w1.x, xv[u], a4); a5 = fmaf(w1.y, xv[u], a5);
                a6 = fmaf(w1.z, xv[u], a6); a7 = fmaf(w1.w, xv[u], a7);
            }
        }
        sm.l.part[q][0][f] = a0; sm.l.part[q][1][f] = a1;
        sm.l.part[q][2][f] = a2; sm.l.part[q][3][f] = a3;
        sm.l.part[q][4][f] = a4; sm.l.part[q][5][f] = a5;
        sm.l.part[q][6][f] = a6; sm.l.part[q][7][f] = a7;
        __syncthreads();
        float aggv = 0.f;
#pragma unroll
        for (int w = 0; w < 8; ++w) aggv += sm.l.part[w][q][f];
        aggv *= rnorm;
        sm.l.agg[q][f] = aggv;
        __syncthreads();
        float mv = emsg;
#pragma unroll 8
        for (int c = 0; c < 64; ++c) mv = fmaf(sm.l.agg[q][c], WmL[c * 64 + f], mv);
        mv = fmaxf(mv, 0.f);
        sm.l.msg[q][f] = mv;
        __syncthreads();
        float h = hx;
#pragma unroll 8
        for (int c = 0; c < 64; ++c) h = fmaf(sm.l.msg[q][c], WuL[(64 + c) * 64 + f], h);
        if (l != 3) {
            h = fmaxf(h, 0.f);
            float* xout = (l == 0) ? xA : (l == 1) ? xB : xA;
            st_coh(&xout[(size_t)(g0 + q) * 64 + f], h);
            xreg = h;
            sm.l.x[q][f] = h;     // made visible by arrive's __syncthreads
            arrive(flags, l);
        } else {
            out[(size_t)(g0 + q) * 64 + f] = h;
        }
    }
}

extern "C" void kernel_launch(void* const* d_in, const int* in_sizes, int n_in,
                              void* d_out, int out_size, void* d_ws, size_t ws_size,
                              hipStream_t stream) {
    const float* nf  = (const float*)d_in[0];
    const float* adj = (const float*)d_in[1];
    const float* wvu = (const float*)d_in[2];
    const float* Wi  = (const float*)d_in[3];
    const float* bi  = (const float*)d_in[4];
    const float* Wee = (const float*)d_in[5];
    const float* Wef = (const float*)d_in[6];
    const float* Wm  = (const float*)d_in[7];
    const float* Wu  = (const float*)d_in[8];
    float* out = (float*)d_out;
    float* ws = (float*)d_ws;

    float* xA     = ws;                  // 131072 floats
    float* xB     = ws + 131072;         // 131072
    float* maxenc = ws + 262144;         // 256 line-padded encoded block maxima
    int*   flags  = (int*)(ws + 266240); // 3 * 256 line-padded flags

    // No memset: maxenc uses >=1.0 encoding, flags poll ==1; harness 0xAA
    // poison (and zeros) read as "absent" for both.
    k_all<<<NBLK, NTHR, 0, stream>>>(nf, adj, wvu, Wi, bi, Wee, Wef, Wm, Wu,
                                     out, xA, xB, maxenc, flags);
}

// Round 15
// 136.934 us; speedup vs baseline: 1.7716x; 1.5556x over previous
//
#include <hip/hip_runtime.h>

// Problem constants: B=2, N=1024, U=V=512, F_IN=1, F=64, L=4
#define NTOT 1024
#define HALF 512
#define NBLK 256
#define NTHR 512

// LayerS (24 KB) < offsetof(EdgeS, nfv) (32 KB): nfv survives the union
// switch into the layer phase (needed for local x0 regeneration).
struct EdgeS  { float adjr[8][1024]; float nfv[1024]; float ein[8][64]; };
struct LayerS { float part[8][8][64]; float e[8][64]; float x[8][64];
                float agg[8][64]; float msg[8][64]; };
union SMem { EdgeS e; LayerS l; };

static __device__ __forceinline__ void st_coh(float* p, float v) {
    __hip_atomic_store(p, v, __ATOMIC_RELAXED, __HIP_MEMORY_SCOPE_AGENT);
}
static __device__ __forceinline__ float ld_coh(const float* p) {
    return __hip_atomic_load((float*)p, __ATOMIC_RELAXED, __HIP_MEMORY_SCOPE_AGENT);
}

// Flag relay (flags poll ==1; 0xAA poison reads as unset -> no zero-init).
// Arrive: drain own coherent stores, block barrier, one flag store.
// Waits: lanes spin independently on one flag each, then __syncthreads.
// Spin caps degrade a residency failure to wrong results, never a hang.
static __device__ __forceinline__ void arrive(int* flags, int idx) {
    asm volatile("s_waitcnt vmcnt(0) lgkmcnt(0)" ::: "memory");
    __syncthreads();
    if (threadIdx.x == 0)
        __hip_atomic_store(&flags[(idx * NBLK + blockIdx.x) * 16], 1,
                           __ATOMIC_RELAXED, __HIP_MEMORY_SCOPE_AGENT);
}
static __device__ __forceinline__ void wait64(const int* flags, int idx, int pbase) {
    if (threadIdx.x < 64) {
        const int* fp = &flags[(idx * NBLK + pbase + threadIdx.x) * 16];
        int spins = 0;
        while (__hip_atomic_load((int*)fp, __ATOMIC_RELAXED,
                                 __HIP_MEMORY_SCOPE_AGENT) != 1) {
            if (++spins > (1 << 22)) break;
            __builtin_amdgcn_s_sleep(1);
        }
    }
    __syncthreads();
}
static __device__ __forceinline__ void wait_all(const int* flags, int idx) {
    if (threadIdx.x < NBLK) {
        const int* fp = &flags[(idx * NBLK + threadIdx.x) * 16];
        int spins = 0;
        while (__hip_atomic_load((int*)fp, __ATOMIC_RELAXED,
                                 __HIP_MEMORY_SCOPE_AGENT) != 1) {
            if (++spins > (1 << 22)) break;
            __builtin_amdgcn_s_sleep(2);
        }
    }
    __syncthreads();
}

__global__ void __launch_bounds__(NTHR, 2) k_all(
    const float* __restrict__ nf, const float* __restrict__ adj,
    const float* __restrict__ wvu, const float* __restrict__ Wi,
    const float* __restrict__ bi, const float* __restrict__ Wee,
    const float* __restrict__ Wef, const float* __restrict__ Wm,
    const float* __restrict__ Wu, float* __restrict__ out,
    float* __restrict__ xe1, float* __restrict__ xe2,
    float* __restrict__ xe3, float* __restrict__ normf,
    int* __restrict__ flags)
{
    __shared__ SMem sm;
    __shared__ float wqv[512][8];   // persistent: W for this block's 8 rows
    __shared__ float snorm[8];
    __shared__ float swred[8];
    const int bid = blockIdx.x, tid = threadIdx.x;
    const int g0 = bid * 8;
    const int b = g0 >> 10, i0 = g0 & 1023;
    const bool top = (i0 < 512);
    const int lane = tid & 63, wave = tid >> 6;
    const int pbase = b * 128 + (top ? 64 : 0);   // producers of cross-half x

    // ---------- Phase A: norm colsum partials (contiguous, exact atomics) ---
    {
        int cb = bid >> 7, sub = bid & 127;
        int cc = sub & 1, rc = sub >> 1;
        int col = cc * 512 + tid;
        const float* p = adj + (size_t)cb * NTOT * NTOT + (size_t)rc * 16 * NTOT + col;
        float s = 0.f;
#pragma unroll
        for (int r = 0; r < 16; ++r) s += 1.0f - p[(size_t)r * NTOT];
        atomicAdd(&normf[cb * NTOT + col], s);   // exact small integers
    }
    arrive(flags, 0);   // normf partials published

    // ---------- stage wqv + adjr + nfv (hides bar0 skew) --------------------
    if (top) {
        const float* src = wvu + (size_t)b * 262144 + (size_t)tid * 512 + i0;
        float4 v0 = *(const float4*)(src);
        float4 v1 = *(const float4*)(src + 4);
        *(float4*)&wqv[tid][0] = v0;
        *(float4*)&wqv[tid][4] = v1;
    } else {
        const float* wsrc = wvu + (size_t)b * 262144 + (size_t)(i0 - 512) * 512;
        for (int t = tid; t < 4096; t += NTHR) {
            int r = t >> 9, j = t & 511;
            wqv[j][r] = wsrc[r * 512 + j];
        }
    }
    {
        const float4* asrc = (const float4*)(adj + (size_t)b * 1048576 + (size_t)i0 * 1024);
        float4* adst = (float4*)sm.e.adjr;
        for (int t = tid; t < 2048; t += NTHR) adst[t] = asrc[t];
        if (tid < 256) ((float4*)sm.e.nfv)[tid] = ((const float4*)(nf + b * 1024))[tid];
    }
    __syncthreads();
    const float Wif = Wi[lane];
    const float bif = bi[lane];
    float xreg = fmaxf(fmaf(nf[b * 1024 + i0 + wave], Wif, bif), 0.f);

    // ---------- edge compute (no cross-block data) --------------------------
    const int row = wave;
    float acc;
    {
        int sameoff = top ? 0 : 512;
        int crossoff = top ? 512 : 0;
        float sp = 0.f, smv = 0.f;
#pragma unroll
        for (int it = 0; it < 8; ++it) {
            int j = sameoff + it * 64 + lane;
            float m = 1.0f - sm.e.adjr[row][j];
            float x = sm.e.nfv[j];
            sp = fmaf(m, fmaxf(x, 0.f), sp);
            smv = fmaf(m, fmaxf(-x, 0.f), smv);
        }
#pragma unroll
        for (int o = 32; o > 0; o >>= 1) {
            sp += __shfl_xor(sp, o, 64);
            smv += __shfl_xor(smv, o, 64);
        }
        float W0 = 0.f, W1 = 0.f;
        if (lane < 63) { W0 = Wee[lane]; W1 = Wee[63 + lane]; }
        acc = fabsf(W1) * (W1 > 0.f ? sp : smv);
        const float* arow = &sm.e.adjr[row][crossoff];
        const float* nrow = &sm.e.nfv[crossoff];
#pragma unroll 4
        for (int qq = 0; qq < 128; ++qq) {
            float4 a4 = *(const float4*)(arow + qq * 4);
            float4 n4 = *(const float4*)(nrow + qq * 4);
            float w0 = wqv[qq * 4 + 0][row];
            float w1 = wqv[qq * 4 + 1][row];
            float w2 = wqv[qq * 4 + 2][row];
            float w3 = wqv[qq * 4 + 3][row];
            float c;
            c = fmaxf(fmaf(w0, W0, n4.x * W1), 0.f); acc = fmaf(1.0f - a4.x, c, acc);
            c = fmaxf(fmaf(w1, W0, n4.y * W1), 0.f); acc = fmaf(1.0f - a4.y, c, acc);
            c = fmaxf(fmaf(w2, W0, n4.z * W1), 0.f); acc = fmaf(1.0f - a4.z, c, acc);
            c = fmaxf(fmaf(w3, W0, n4.w * W1), 0.f); acc = fmaf(1.0f - a4.w, c, acc);
        }
    }
    wait_all(flags, 0);   // normf globally complete (hidden by edge work)

    // ---------- norms: own 8 + global max -----------------------------------
    if (tid < 8) snorm[tid] = fmaxf(ld_coh(&normf[b * NTOT + i0 + tid]), 1.0f);
    {
        float m = 1.0f;
#pragma unroll
        for (int u = 0; u < 4; ++u)
            m = fmaxf(m, ld_coh(&normf[tid * 4 + u]));
#pragma unroll
        for (int o = 32; o > 0; o >>= 1) m = fmaxf(m, __shfl_xor(m, o, 64));
        if (lane == 0) swred[wave] = m;
    }
    __syncthreads();

    // ---------- finish edge: divide + 64x64 matmul (Wef via L1) -------------
    float eval;
    {
        float nv = snorm[row];
        float nmaxv = fmaxf(fmaxf(fmaxf(swred[0], swred[1]), fmaxf(swred[2], swred[3])),
                            fmaxf(fmaxf(swred[4], swred[5]), fmaxf(swred[6], swred[7])));
        float ein = (lane < 63) ? (acc * (1.0f / nv)) : (nv / nmaxv);
        sm.e.ein[row][lane] = ein;
        __syncthreads();
        float acc2 = 0.f;
#pragma unroll 8
        for (int c = 0; c < 64; ++c)
            acc2 = fmaf(sm.e.ein[row][c], Wef[c * 64 + lane], acc2);
        eval = fmaxf(acc2, 0.f);
    }
    __syncthreads();   // EdgeS adjr/ein dead; LayerS leaves nfv intact

    // ---------- layers ------------------------------------------------------
    const int f = lane, q = wave;
    sm.l.e[q][f] = eval;
    sm.l.x[q][f] = xreg;
    __syncthreads();
    const float rnorm = 1.0f / snorm[q];
    const int crossoff = top ? 512 : 0;
    const int jbase = q * 64;

    // ----- layer 0 (peeled): cross-half x0 regenerated from nfv, no wait ----
    {
        float emsg = 0.f, hx = 0.f;
#pragma unroll 8
        for (int c = 0; c < 64; ++c) {
            emsg = fmaf(sm.l.e[q][c], Wm[(64 + c) * 64 + f], emsg);
            hx   = fmaf(sm.l.x[q][c], Wu[c * 64 + f], hx);
        }
        float a0 = 0, a1 = 0, a2 = 0, a3 = 0, a4 = 0, a5 = 0, a6 = 0, a7 = 0;
#pragma unroll
        for (int hh = 0; hh < 2; ++hh) {
            float xv[32];
#pragma unroll
            for (int u = 0; u < 32; ++u)
                xv[u] = fmaxf(fmaf(sm.e.nfv[crossoff + jbase + hh * 32 + u],
                                   Wif, bif), 0.f);
#pragma unroll
            for (int u = 0; u < 32; ++u) {
                int j = jbase + hh * 32 + u;
                float4 w0 = *(const float4*)&wqv[j][0];
                float4 w1 = *(const float4*)&wqv[j][4];
                a0 = fmaf(w0.x, xv[u], a0); a1 = fmaf(w0.y, xv[u], a1);
                a2 = fmaf(w0.z, xv[u], a2); a3 = fmaf(w0.w, xv[u], a3);
                a4 = fmaf(w1.x, xv[u], a4); a5 = fmaf(w1.y, xv[u], a5);
                a6 = fmaf(w1.z, xv[u], a6); a7 = fmaf(w1.w, xv[u], a7);
            }
        }
        sm.l.part[q][0][f] = a0; sm.l.part[q][1][f] = a1;
        sm.l.part[q][2][f] = a2; sm.l.part[q][3][f] = a3;
        sm.l.part[q][4][f] = a4; sm.l.part[q][5][f] = a5;
        sm.l.part[q][6][f] = a6; sm.l.part[q][7][f] = a7;
        __syncthreads();
        float aggv = 0.f;
#pragma unroll
        for (int w = 0; w < 8; ++w) aggv += sm.l.part[w][q][f];
        aggv *= rnorm;
        sm.l.agg[q][f] = aggv;
        __syncthreads();
        float mv = emsg;
#pragma unroll 8
        for (int c = 0; c < 64; ++c) mv = fmaf(sm.l.agg[q][c], Wm[c * 64 + f], mv);
        mv = fmaxf(mv, 0.f);
        sm.l.msg[q][f] = mv;
        __syncthreads();
        float h = hx;
#pragma unroll 8
        for (int c = 0; c < 64; ++c) h = fmaf(sm.l.msg[q][c], Wu[(64 + c) * 64 + f], h);
        h = fmaxf(h, 0.f);
        st_coh(&xe1[(size_t)(g0 + q) * 64 + f], h);   // write-through publish
        xreg = h;
        sm.l.x[q][f] = h;       // made visible by arrive's __syncthreads
        arrive(flags, 1);
    }

    // ----- layers 1..3: cached reads of write-once buffers ------------------
    for (int l = 1; l < 4; ++l) {
        const float* WmL = Wm + l * 8192;
        const float* WuL = Wu + l * 8192;
        float emsg = 0.f, hx = 0.f;
#pragma unroll 8
        for (int c = 0; c < 64; ++c) {
            emsg = fmaf(sm.l.e[q][c], WmL[(64 + c) * 64 + f], emsg);
            hx   = fmaf(sm.l.x[q][c], WuL[c * 64 + f], hx);
        }
        wait64(flags, l, pbase);   // producers' write-through complete

        const float* xin = (l == 1) ? xe1 : (l == 2) ? xe2 : xe3;
        const float* xb = xin + ((size_t)b * 1024 + (top ? 512 : 0)) * 64 + f;
        float a0 = 0, a1 = 0, a2 = 0, a3 = 0, a4 = 0, a5 = 0, a6 = 0, a7 = 0;
#pragma unroll
        for (int hh = 0; hh < 2; ++hh) {
            float xv[32];
#pragma unroll
            for (int u = 0; u < 32; ++u)
                xv[u] = xb[(size_t)(jbase + hh * 32 + u) * 64];  // CACHED read
#pragma unroll
            for (int u = 0; u < 32; ++u) {
                int j = jbase + hh * 32 + u;
                float4 w0 = *(const float4*)&wqv[j][0];
                float4 w1 = *(const float4*)&wqv[j][4];
                a0 = fmaf(w0.x, xv[u], a0); a1 = fmaf(w0.y, xv[u], a1);
                a2 = fmaf(w0.z, xv[u], a2); a3 = fmaf(w0.w, xv[u], a3);
                a4 = fmaf(w1.x, xv[u], a4); a5 = fmaf(w1.y, xv[u], a5);
                a6 = fmaf(w1.z, xv[u], a6); a7 = fmaf(w1.w, xv[u], a7);
            }
        }
        sm.l.part[q][0][f] = a0; sm.l.part[q][1][f] = a1;
        sm.l.part[q][2][f] = a2; sm.l.part[q][3][f] = a3;
        sm.l.part[q][4][f] = a4; sm.l.part[q][5][f] = a5;
        sm.l.part[q][6][f] = a6; sm.l.part[q][7][f] = a7;
        __syncthreads();
        float aggv = 0.f;
#pragma unroll
        for (int w = 0; w < 8; ++w) aggv += sm.l.part[w][q][f];
        aggv *= rnorm;
        sm.l.agg[q][f] = aggv;
        __syncthreads();
        float mv = emsg;
#pragma unroll 8
        for (int c = 0; c < 64; ++c) mv = fmaf(sm.l.agg[q][c], WmL[c * 64 + f], mv);
        mv = fmaxf(mv, 0.f);
        sm.l.msg[q][f] = mv;
        __syncthreads();
        float h = hx;
#pragma unroll 8
        for (int c = 0; c < 64; ++c) h = fmaf(sm.l.msg[q][c], WuL[(64 + c) * 64 + f], h);
        if (l != 3) {
            h = fmaxf(h, 0.f);
            float* xout = (l == 1) ? xe2 : xe3;
            st_coh(&xout[(size_t)(g0 + q) * 64 + f], h);
            xreg = h;
            sm.l.x[q][f] = h;
            arrive(flags, l + 1);
        } else {
            out[(size_t)(g0 + q) * 64 + f] = h;
        }
    }
}

extern "C" void kernel_launch(void* const* d_in, const int* in_sizes, int n_in,
                              void* d_out, int out_size, void* d_ws, size_t ws_size,
                              hipStream_t stream) {
    const float* nf  = (const float*)d_in[0];
    const float* adj = (const float*)d_in[1];
    const float* wvu = (const float*)d_in[2];
    const float* Wi  = (const float*)d_in[3];
    const float* bi  = (const float*)d_in[4];
    const float* Wee = (const float*)d_in[5];
    const float* Wef = (const float*)d_in[6];
    const float* Wm  = (const float*)d_in[7];
    const float* Wu  = (const float*)d_in[8];
    float* out = (float*)d_out;
    float* ws = (float*)d_ws;

    float* xe1   = ws;                   // 131072 floats each, write-once
    float* xe2   = ws + 131072;
    float* xe3   = ws + 262144;
    float* normf = ws + 393216;          // 2048 (needs zero-init)
    int*   flags = (int*)(ws + 395264);  // 4 * 256 line-padded, poison-as-unset

    hipMemsetAsync(normf, 0, 2048 * sizeof(float), stream);

    k_all<<<NBLK, NTHR, 0, stream>>>(nf, adj, wvu, Wi, bi, Wee, Wef, Wm, Wu,
                                     out, xe1, xe2, xe3, normf, flags);
}